// Round 5
// baseline (247.790 us; speedup 1.0000x reference)
//
#include <hip/hip_runtime.h>
#include <hip/hip_bf16.h>

using bf16x8 = __attribute__((ext_vector_type(8))) short;
using f32x4  = __attribute__((ext_vector_type(4))) float;

constexpr int cV  = 50257;
constexpr int cVp = 50432;          // padded rows for bf16 W (197*256)
constexpr int cD  = 128;
constexpr int cN  = 512;
constexpr int cS  = 256;

#define PHI_F    1.6180339887498949f
#define INV2PI_F 0.15915494309189535f
#define SQRT2_F  1.4142135623730951f

__device__ __forceinline__ float fract1(float x) { return x - floorf(x); }

#if __has_builtin(__builtin_amdgcn_sinf)
__device__ __forceinline__ float sin_rev(float r) { return __builtin_amdgcn_sinf(r); }   // sin(2*pi*r)
__device__ __forceinline__ float cos_rev(float r) { return __builtin_amdgcn_cosf(r); }   // cos(2*pi*r)
#else
__device__ __forceinline__ float sin_rev(float r) { return __sinf(r * 6.2831853071795865f); }
__device__ __forceinline__ float cos_rev(float r) { return __cosf(r * 6.2831853071795865f); }
#endif

__device__ __forceinline__ unsigned short f2bf(float f) {
  unsigned u = __float_as_uint(f);
  unsigned r = (u + 0x7FFFu + ((u >> 16) & 1u)) >> 16;
  return (unsigned short)r;
}

// ------ setup: mc prep (0-255) + proj transpose (256-767) + W bf16 pack (768+) ------
__global__ void k_setup(const int* __restrict__ tokens, const float* __restrict__ emb,
                        float2* __restrict__ mc,
                        const float* __restrict__ pr, const float* __restrict__ pi,
                        float* __restrict__ pTR, float* __restrict__ pTI,
                        const float* __restrict__ W, unsigned short* __restrict__ Wbf) {
  int blk = blockIdx.x;
  if (blk < 256) {
    int idx = blk * 256 + threadIdx.x;             // 65536 = S * (B*D)
    int t = idx & 255, s = idx >> 8;
    int b = t >> 7, d = t & 127;
    int tok = tokens[b * cS + s];
    float w  = emb[tok * (2 * cD) + d];
    float be = emb[tok * (2 * cD) + cD + d];
    float m2 = SQRT2_F * INV2PI_F / (1.f + fabsf(w));
    float c  = fmaf((float)s, PHI_F, be) * INV2PI_F + 0.125f;
    mc[idx] = make_float2(m2, c);
  } else if (blk < 768) {
    int idx = (blk - 256) * 256 + threadIdx.x;     // L*N*D = 131072
    int l = idx >> 16, rem = idx & 65535;
    int n = rem >> 7, d = rem & 127;
    int src = (l * cD + d) * cN + n;
    pTR[idx] = pr[src];
    pTI[idx] = pi[src];
  } else {
    int idx = (blk - 768) * 256 + threadIdx.x;     // 806912 = 50432 rows * 16
    int row = idx >> 4, c0 = (idx & 15) * 8;
    ushort4 o0 = {0,0,0,0}, o1 = {0,0,0,0};
    if (row < cV) {
      float4 w0 = *(const float4*)(W + (size_t)row * cD + c0);
      float4 w1 = *(const float4*)(W + (size_t)row * cD + c0 + 4);
      o0 = { f2bf(w0.x), f2bf(w0.y), f2bf(w0.z), f2bf(w0.w) };
      o1 = { f2bf(w1.x), f2bf(w1.y), f2bf(w1.z), f2bf(w1.w) };
    }
    unsigned short* dst = Wbf + (size_t)row * cD + c0;
    *(ushort4*)dst = o0;
    *(ushort4*)(dst + 4) = o1;
  }
}

// ---------------- sequential scan -------------------------------------------
__global__ void k_scan(const float2* __restrict__ mc, float* __restrict__ states) {
  int t = threadIdx.x;                              // 256 = B*D
  int b = t >> 7, d = t & 127;
  float2 buf[8];
#pragma unroll
  for (int i = 0; i < 8; ++i) buf[i] = mc[i * 256 + t];
  float sv = 0.f;
  float* out = states + (b * cS) * cD + d;
#pragma unroll 8
  for (int s = 0; s < cS; ++s) {
    float2 v = buf[s & 7];
    if (s + 8 < cS) buf[s & 7] = mc[(s + 8) * 256 + t];
    float r = fmaf(sv, v.x, v.y);
    sv = sin_rev(fract1(r));
    out[s * cD] = sv * SQRT2_F;
  }
}

// ---------------- fused per-layer: attn (blocks 0-255) || fsum (256-511) ----
__global__ __launch_bounds__(512) void k_layer(const float* __restrict__ x, const float* __restrict__ states,
                                               const float* __restrict__ wq, const float* __restrict__ bq,
                                               const float* __restrict__ wk, const float* __restrict__ bk,
                                               const float* __restrict__ Wf, const float* __restrict__ Bf,
                                               float* __restrict__ ctx, float* __restrict__ U, float* __restrict__ Vv) {
  int blk = blockIdx.x;
  if (blk < 256) {
    __shared__ __align__(16) float qrow[2][256];
    __shared__ float Psum[2][256];
    __shared__ float redm[2][4], reds[2][4];
    __shared__ float cred[2][256];
    __shared__ __align__(16) float rkl[128], bkl[128];
    int b = blk >> 7, qp = blk & 127;
    int sub = threadIdx.x >> 8;
    int t = threadIdx.x & 255;
    int q = qp * 2 + sub;
    if (threadIdx.x < 128) {
      int hd = threadIdx.x;
      rkl[hd] = INV2PI_F / (1.f + fabsf(wk[hd]));
      bkl[hd] = bk[hd] * INV2PI_F;
    }
    if (t < 128) {
      int hd = t;
      float rq = 1.f / (1.f + fabsf(wq[hd]));
      float thq = fmaf(x[(b * cS + q) * cD + hd], rq, fmaf((float)q, PHI_F, bq[hd])) * INV2PI_F;
      float fq = fract1(thq);
      qrow[sub][hd]       = cos_rev(fq);
      qrow[sub][128 + hd] = sin_rev(fq);
    }
    Psum[sub][t] = 0.f;
    __syncthreads();
    bool act = (t <= q);
    float sc[8];
    const float4* Sr = (const float4*)(states + (b * cS + t) * cD);
#pragma unroll
    for (int h = 0; h < 8; ++h) {
      float sacc = 0.f;
#pragma unroll
      for (int j = 0; j < 4; ++j) {
        float4 sv4 = Sr[h * 4 + j];
        int hd = h * 16 + j * 4;
        float sva[4] = { sv4.x, sv4.y, sv4.z, sv4.w };
#pragma unroll
        for (int c = 0; c < 4; ++c) {
          float f = fract1(fmaf(sva[c], rkl[hd + c], bkl[hd + c]));
          float ck = cos_rev(f), sk = sin_rev(f);
          sacc = fmaf(qrow[sub][hd + c], ck, fmaf(qrow[sub][128 + hd + c], sk, sacc));
        }
      }
      sc[h] = act ? sacc * 0.17677669529663689f : -3.0e38f;
    }
    int wid = t >> 6;
    for (int h = 0; h < 8; ++h) {
      float v = sc[h];
#pragma unroll
      for (int off = 32; off; off >>= 1) v = fmaxf(v, __shfl_xor(v, off, 64));
      if ((t & 63) == 0) redm[sub][wid] = v;
      __syncthreads();
      float m = fmaxf(fmaxf(redm[sub][0], redm[sub][1]), fmaxf(redm[sub][2], redm[sub][3]));
      float p = act ? __expf(sc[h] - m) : 0.f;
      float ps = p;
#pragma unroll
      for (int off = 32; off; off >>= 1) ps += __shfl_xor(ps, off, 64);
      if ((t & 63) == 0) reds[sub][wid] = ps;
      __syncthreads();
      float tot = reds[sub][0] + reds[sub][1] + reds[sub][2] + reds[sub][3];
      Psum[sub][t] += p / tot;
    }
    __syncthreads();
    int d = t & 127, half = t >> 7;
    float acc = 0.f;
    int k0 = half * 128;
    int kend = min(k0 + 128, q + 1);
    for (int kk = k0; kk < kend; ++kk)
      acc = fmaf(Psum[sub][kk], states[(b * cS + kk) * cD + d], acc);
    cred[sub][t] = acc;
    __syncthreads();
    if (half == 0) ctx[(b * cS + q) * cD + d] = cred[sub][t] + cred[sub][t + 128];
  } else {
    int fblk = blk - 256;
    int ns = fblk & 15, tg = fblk >> 4;
    constexpr int P = 130;
    __shared__ __align__(16) float finv[32 * P];
    __shared__ __align__(16) float fb[32 * P];
    __shared__ __align__(16) float xl[32 * 128];
    int t = threadIdx.x;
#pragma unroll
    for (int i = 0; i < 8; ++i) {
      int idx = t + i * 512;
      int rl = idx >> 7, d = idx & 127;
      int g = (ns * 32 + rl) * cD + d;
      finv[rl * P + d] = INV2PI_F / (1.f + fabsf(Wf[g]));
      fb[rl * P + d]   = Bf[g] * INV2PI_F;
      xl[idx] = x[(tg * 32 + rl) * cD + d];
    }
    __syncthreads();
    int nl = t & 31, tli = t >> 5;
#pragma unroll
    for (int p = 0; p < 2; ++p) {
      int tl = p * 16 + tli;
      int T = tg * 32 + tl;
      float srev = (float)(T & 255) * INV2PI_F;
      float uc = 0.f, us = 0.f;
      const float* fi  = finv + nl * P;
      const float* fbp = fb + nl * P;
      const float* xr  = xl + tl * 128;
#pragma unroll 4
      for (int d = 0; d < cD; d += 2) {
        float2 fiv = *(const float2*)(fi + d);
        float2 fbv = *(const float2*)(fbp + d);
        float2 xv  = *(const float2*)(xr + d);
        float f0 = fract1(fmaf(xv.x, fiv.x, fbv.x) + srev);
        float f1 = fract1(fmaf(xv.y, fiv.y, fbv.y) + srev);
        uc += cos_rev(f0);
        us += sin_rev(f0);
        uc += cos_rev(f1);
        us += sin_rev(f1);
      }
      U[T * cN + ns * 32 + nl]  = uc;
      Vv[T * cN + ns * 32 + nl] = us;
    }
  }
}

// ---------------- res projection + attn-out + combine (per layer) ------------
// grid 512 (1 token/block) x 256 thr; thread: d4=t&31 (4-col group), nh=t>>5 (8 n-chunks)
__global__ __launch_bounds__(256) void k_res(const float* __restrict__ U, const float* __restrict__ Vv,
                                             const float* __restrict__ pTR, const float* __restrict__ pTI,
                                             const float* __restrict__ ctx, const float* __restrict__ x,
                                             const float* __restrict__ w_out, const float* __restrict__ b_out,
                                             const float* __restrict__ out_scale,
                                             const float* __restrict__ attn_scale, const float* __restrict__ res_scale,
                                             int l, float* __restrict__ xout, unsigned short* __restrict__ xbf) {
  int T = blockIdx.x;
  int t = threadIdx.x;
  __shared__ __align__(16) float uvU[512], uvV[512];
  __shared__ __align__(16) float4 part[8][32];
  uvU[t]       = U[T * cN + t];
  uvU[t + 256] = U[T * cN + 256 + t];
  uvV[t]       = Vv[T * cN + t];
  uvV[t + 256] = Vv[T * cN + 256 + t];
  __syncthreads();
  int d4 = t & 31, nh = t >> 5;
  float a0 = 0.f, a1 = 0.f, a2 = 0.f, a3 = 0.f;
  const float* prB = pTR + (size_t)(l * cN) * cD + d4 * 4;
  const float* piB = pTI + (size_t)(l * cN) * cD + d4 * 4;
  int n0 = nh * 64;
#pragma unroll 4
  for (int n = n0; n < n0 + 64; ++n) {
    float4 pr = *(const float4*)(prB + n * cD);
    float4 pi = *(const float4*)(piB + n * cD);
    float wr = uvU[n], wi = uvV[n];
    a0 = fmaf(wr, pr.x, fmaf(wi, pi.x, a0));
    a1 = fmaf(wr, pr.y, fmaf(wi, pi.y, a1));
    a2 = fmaf(wr, pr.z, fmaf(wi, pi.z, a2));
    a3 = fmaf(wr, pr.w, fmaf(wi, pi.w, a3));
  }
  if (nh > 0) part[nh][d4] = make_float4(a0, a1, a2, a3);
  __syncthreads();
  if (nh == 0) {
    float rr[4] = { a0, a1, a2, a3 };
#pragma unroll
    for (int j = 1; j < 8; ++j) {
      float4 p = part[j][d4];
      rr[0] += p.x; rr[1] += p.y; rr[2] += p.z; rr[3] += p.w;
    }
    int s = T & 255;
    int di = d4 * 4;
    float4 cx  = *(const float4*)(ctx + T * cD + di);
    float4 wo  = *(const float4*)(w_out + l * cD + di);
    float4 bo  = *(const float4*)(b_out + l * cD + di);
    float4 osc = *(const float4*)(out_scale + l * cD + di);
    float4 xv  = *(const float4*)(x + T * cD + di);
    float as = attn_scale[l], rs = res_scale[l];
    float sphi = (float)s * PHI_F;
    float cxa[4] = { cx.x, cx.y, cx.z, cx.w };
    float woa[4] = { wo.x, wo.y, wo.z, wo.w };
    float boa[4] = { bo.x, bo.y, bo.z, bo.w };
    float osa[4] = { osc.x, osc.y, osc.z, osc.w };
    float xva[4] = { xv.x, xv.y, xv.z, xv.w };
    float oa[4];
#pragma unroll
    for (int c = 0; c < 4; ++c) {
      float th = fmaf(cxa[c], 1.f / (1.f + fabsf(woa[c])), boa[c]) + sphi;
      float f = fract1(th * INV2PI_F);
      float ao = osa[c] * (cos_rev(f) + sin_rev(f));
      float r = rr[c];
      float sil = r / (1.f + __expf(-r));
      oa[c] = fmaf(as, ao, fmaf(rs, sil, xva[c]));
    }
    *(float4*)(xout + T * cD + di) = make_float4(oa[0], oa[1], oa[2], oa[3]);
    if (xbf) {
      ushort4 b4 = { f2bf(oa[0]), f2bf(oa[1]), f2bf(oa[2]), f2bf(oa[3]) };
      *(ushort4*)(xbf + T * cD + di) = b4;
    }
  }
}

// ---------------- final logits GEMM: write-locality-first --------------------
// grid 197 (v-chunks of 256) x 1024 thr (16 waves). Block = ALL 512 m x 256 v.
// Wave = 32m x 256v: fm=2, fv=16, acc = 128 VGPR. No LDS, no barriers.
// Each output row receives a contiguous aligned 1KB chunk per block (DRAM page hit).
__global__ __launch_bounds__(1024) void k_gemm(const unsigned short* __restrict__ Xbf,
                                               const unsigned short* __restrict__ Wbf,
                                               float* __restrict__ out) {
  int t = threadIdx.x;
  int v0 = blockIdx.x * 256;
  int wid = t >> 6, lane = t & 63, lr = lane & 15, lk = lane >> 4;
  int wm = wid * 32;
  const bf16x8* Xp = (const bf16x8*)Xbf;            // row-major: row*16 + ks*4 + lk
  const bf16x8* Wp = (const bf16x8*)Wbf;
  f32x4 acc[2][16];
#pragma unroll
  for (int fm = 0; fm < 2; ++fm)
#pragma unroll
    for (int fv = 0; fv < 16; ++fv) acc[fm][fv] = (f32x4){0.f, 0.f, 0.f, 0.f};
#pragma unroll
  for (int ks = 0; ks < 4; ++ks) {
    bf16x8 a0 = Xp[(wm + lr) * 16 + ks * 4 + lk];
    bf16x8 a1 = Xp[(wm + 16 + lr) * 16 + ks * 4 + lk];
#pragma unroll
    for (int fv = 0; fv < 16; ++fv) {
      bf16x8 b = Wp[(size_t)(v0 + fv * 16 + lr) * 16 + ks * 4 + lk];
      acc[0][fv] = __builtin_amdgcn_mfma_f32_16x16x32_bf16(a0, b, acc[0][fv], 0, 0, 0);
      acc[1][fv] = __builtin_amdgcn_mfma_f32_16x16x32_bf16(a1, b, acc[1][fv], 0, 0, 0);
    }
  }
  // epilogue: dword stores; L2 combines 64B lane-segments into full lines;
  // block covers cols v0..v0+255 for every row -> 1KB/row contiguous.
#pragma unroll
  for (int fm = 0; fm < 2; ++fm) {
    size_t rbase = (size_t)(wm + fm * 16 + lk * 4) * cV;
#pragma unroll
    for (int fv = 0; fv < 16; ++fv) {
      int col = v0 + fv * 16 + lr;
      if (col < cV) {
#pragma unroll
        for (int r = 0; r < 4; ++r)
          out[rbase + (size_t)r * cV + col] = acc[fm][fv][r];
      }
    }
  }
}

extern "C" void kernel_launch(void* const* d_in, const int* in_sizes, int n_in,
                              void* d_out, int out_size, void* d_ws, size_t ws_size,
                              hipStream_t stream) {
  const int*   tokens    = (const int*)d_in[0];
  const float* emb       = (const float*)d_in[1];
  const float* wq        = (const float*)d_in[2];
  const float* bq        = (const float*)d_in[3];
  const float* wk        = (const float*)d_in[4];
  const float* bk        = (const float*)d_in[5];
  const float* w_out     = (const float*)d_in[6];
  const float* b_out     = (const float*)d_in[7];
  const float* out_scale = (const float*)d_in[8];
  const float* Wf        = (const float*)d_in[9];
  const float* Bf        = (const float*)d_in[10];
  const float* pr        = (const float*)d_in[11];
  const float* pi        = (const float*)d_in[12];
  const float* attn_s    = (const float*)d_in[13];
  const float* res_s     = (const float*)d_in[14];
  const float* out_proj  = (const float*)d_in[15];
  float* out = (float*)d_out;
  float* ws  = (float*)d_ws;

  float*  states = ws;                     // 65536
  float*  x1     = ws + 65536;             // 65536
  float*  x2     = ws + 131072;            // 65536
  float*  ctx    = ws + 196608;            // 65536
  float2* mc     = (float2*)(ws + 262144); // 131072 floats
  float*  U      = ws + 393216;            // 262144
  float*  Vv     = ws + 655360;            // 262144
  float*  pTR    = ws + 917504;            // 131072
  float*  pTI    = ws + 1048576;           // 131072
  unsigned short* X2bf = (unsigned short*)(ws + 1179648); // 65536 ushorts
  unsigned short* Wbf  = (unsigned short*)(ws + 1212416); // 50432*128 ushorts (12.9MB)

  k_setup<<<768 + (cVp * 16) / 256, 256, 0, stream>>>(tokens, emb, mc, pr, pi, pTR, pTI,
                                                      out_proj, Wbf);
  k_scan<<<1, 256, 0, stream>>>(mc, states);

  const float* xin = states;
  float* xouts[2] = { x1, x2 };
  for (int l = 0; l < 2; ++l) {
    k_layer<<<512, 512, 0, stream>>>(xin, states, wq + l * 128, bq + l * 128,
                                     wk + l * 128, bk + l * 128,
                                     Wf + l * 65536, Bf + l * 65536, ctx, U, Vv);
    k_res<<<512, 256, 0, stream>>>(U, Vv, pTR, pTI, ctx, xin, w_out, b_out, out_scale,
                                   attn_s, res_s, l, xouts[l],
                                   (l == 1) ? X2bf : (unsigned short*)nullptr);
    xin = xouts[l];
  }
  k_gemm<<<(cV + 255) / 256, 1024, 0, stream>>>(X2bf, Wbf, out);
}

// Round 6
// 176.426 us; speedup vs baseline: 1.4045x; 1.4045x over previous
//
#include <hip/hip_runtime.h>
#include <hip/hip_bf16.h>

using bf16x8 = __attribute__((ext_vector_type(8))) short;
using f32x4  = __attribute__((ext_vector_type(4))) float;

constexpr int cV  = 50257;
constexpr int cVp = 50688;          // padded rows for bf16 W (99*512)
constexpr int cD  = 128;
constexpr int cN  = 512;
constexpr int cS  = 256;

#define PHI_F    1.6180339887498949f
#define INV2PI_F 0.15915494309189535f
#define SQRT2_F  1.4142135623730951f

__device__ __forceinline__ float fract1(float x) { return x - floorf(x); }

#if __has_builtin(__builtin_amdgcn_sinf)
__device__ __forceinline__ float sin_rev(float r) { return __builtin_amdgcn_sinf(r); }   // sin(2*pi*r)
__device__ __forceinline__ float cos_rev(float r) { return __builtin_amdgcn_cosf(r); }   // cos(2*pi*r)
#else
__device__ __forceinline__ float sin_rev(float r) { return __sinf(r * 6.2831853071795865f); }
__device__ __forceinline__ float cos_rev(float r) { return __cosf(r * 6.2831853071795865f); }
#endif

__device__ __forceinline__ unsigned short f2bf(float f) {
  unsigned u = __float_as_uint(f);
  unsigned r = (u + 0x7FFFu + ((u >> 16) & 1u)) >> 16;
  return (unsigned short)r;
}

// ------ setup: mc prep (0-255) + proj transpose (256-767) + W bf16 pack (768+) ------
__global__ void k_setup(const int* __restrict__ tokens, const float* __restrict__ emb,
                        float2* __restrict__ mc,
                        const float* __restrict__ pr, const float* __restrict__ pi,
                        float* __restrict__ pTR, float* __restrict__ pTI,
                        const float* __restrict__ W, unsigned short* __restrict__ Wbf) {
  int blk = blockIdx.x;
  if (blk < 256) {
    int idx = blk * 256 + threadIdx.x;             // 65536 = S * (B*D)
    int t = idx & 255, s = idx >> 8;
    int b = t >> 7, d = t & 127;
    int tok = tokens[b * cS + s];
    float w  = emb[tok * (2 * cD) + d];
    float be = emb[tok * (2 * cD) + cD + d];
    float m2 = SQRT2_F * INV2PI_F / (1.f + fabsf(w));
    float c  = fmaf((float)s, PHI_F, be) * INV2PI_F + 0.125f;
    mc[idx] = make_float2(m2, c);
  } else if (blk < 768) {
    int idx = (blk - 256) * 256 + threadIdx.x;     // L*N*D = 131072
    int l = idx >> 16, rem = idx & 65535;
    int n = rem >> 7, d = rem & 127;
    int src = (l * cD + d) * cN + n;
    pTR[idx] = pr[src];
    pTI[idx] = pi[src];
  } else {
    int idx = (blk - 768) * 256 + threadIdx.x;     // cVp rows * 16
    int row = idx >> 4, c0 = (idx & 15) * 8;
    ushort4 o0 = {0,0,0,0}, o1 = {0,0,0,0};
    if (row < cV) {
      float4 w0 = *(const float4*)(W + (size_t)row * cD + c0);
      float4 w1 = *(const float4*)(W + (size_t)row * cD + c0 + 4);
      o0 = { f2bf(w0.x), f2bf(w0.y), f2bf(w0.z), f2bf(w0.w) };
      o1 = { f2bf(w1.x), f2bf(w1.y), f2bf(w1.z), f2bf(w1.w) };
    }
    unsigned short* dst = Wbf + (size_t)row * cD + c0;
    *(ushort4*)dst = o0;
    *(ushort4*)(dst + 4) = o1;
  }
}

// ---------------- sequential scan -------------------------------------------
__global__ void k_scan(const float2* __restrict__ mc, float* __restrict__ states) {
  int t = threadIdx.x;                              // 256 = B*D
  int b = t >> 7, d = t & 127;
  float2 buf[8];
#pragma unroll
  for (int i = 0; i < 8; ++i) buf[i] = mc[i * 256 + t];
  float sv = 0.f;
  float* out = states + (b * cS) * cD + d;
#pragma unroll 8
  for (int s = 0; s < cS; ++s) {
    float2 v = buf[s & 7];
    if (s + 8 < cS) buf[s & 7] = mc[(s + 8) * 256 + t];
    float r = fmaf(sv, v.x, v.y);
    sv = sin_rev(fract1(r));
    out[s * cD] = sv * SQRT2_F;
  }
}

// ---------------- fused per-layer: attn (blocks 0-255) || fsum (256-511) ----
__global__ __launch_bounds__(512) void k_layer(const float* __restrict__ x, const float* __restrict__ states,
                                               const float* __restrict__ wq, const float* __restrict__ bq,
                                               const float* __restrict__ wk, const float* __restrict__ bk,
                                               const float* __restrict__ Wf, const float* __restrict__ Bf,
                                               float* __restrict__ ctx, float* __restrict__ U, float* __restrict__ Vv) {
  int blk = blockIdx.x;
  if (blk < 256) {
    __shared__ __align__(16) float qrow[2][256];
    __shared__ float Psum[2][256];
    __shared__ float redm[2][4], reds[2][4];
    __shared__ float cred[2][256];
    __shared__ __align__(16) float rkl[128], bkl[128];
    int b = blk >> 7, qp = blk & 127;
    int sub = threadIdx.x >> 8;
    int t = threadIdx.x & 255;
    int q = qp * 2 + sub;
    if (threadIdx.x < 128) {
      int hd = threadIdx.x;
      rkl[hd] = INV2PI_F / (1.f + fabsf(wk[hd]));
      bkl[hd] = bk[hd] * INV2PI_F;
    }
    if (t < 128) {
      int hd = t;
      float rq = 1.f / (1.f + fabsf(wq[hd]));
      float thq = fmaf(x[(b * cS + q) * cD + hd], rq, fmaf((float)q, PHI_F, bq[hd])) * INV2PI_F;
      float fq = fract1(thq);
      qrow[sub][hd]       = cos_rev(fq);
      qrow[sub][128 + hd] = sin_rev(fq);
    }
    Psum[sub][t] = 0.f;
    __syncthreads();
    bool act = (t <= q);
    float sc[8];
    const float4* Sr = (const float4*)(states + (b * cS + t) * cD);
#pragma unroll
    for (int h = 0; h < 8; ++h) {
      float sacc = 0.f;
#pragma unroll
      for (int j = 0; j < 4; ++j) {
        float4 sv4 = Sr[h * 4 + j];
        int hd = h * 16 + j * 4;
        float sva[4] = { sv4.x, sv4.y, sv4.z, sv4.w };
#pragma unroll
        for (int c = 0; c < 4; ++c) {
          float f = fract1(fmaf(sva[c], rkl[hd + c], bkl[hd + c]));
          float ck = cos_rev(f), sk = sin_rev(f);
          sacc = fmaf(qrow[sub][hd + c], ck, fmaf(qrow[sub][128 + hd + c], sk, sacc));
        }
      }
      sc[h] = act ? sacc * 0.17677669529663689f : -3.0e38f;
    }
    int wid = t >> 6;
    for (int h = 0; h < 8; ++h) {
      float v = sc[h];
#pragma unroll
      for (int off = 32; off; off >>= 1) v = fmaxf(v, __shfl_xor(v, off, 64));
      if ((t & 63) == 0) redm[sub][wid] = v;
      __syncthreads();
      float m = fmaxf(fmaxf(redm[sub][0], redm[sub][1]), fmaxf(redm[sub][2], redm[sub][3]));
      float p = act ? __expf(sc[h] - m) : 0.f;
      float ps = p;
#pragma unroll
      for (int off = 32; off; off >>= 1) ps += __shfl_xor(ps, off, 64);
      if ((t & 63) == 0) reds[sub][wid] = ps;
      __syncthreads();
      float tot = reds[sub][0] + reds[sub][1] + reds[sub][2] + reds[sub][3];
      Psum[sub][t] += p / tot;
    }
    __syncthreads();
    int d = t & 127, half = t >> 7;
    float acc = 0.f;
    int k0 = half * 128;
    int kend = min(k0 + 128, q + 1);
    for (int kk = k0; kk < kend; ++kk)
      acc = fmaf(Psum[sub][kk], states[(b * cS + kk) * cD + d], acc);
    cred[sub][t] = acc;
    __syncthreads();
    if (half == 0) ctx[(b * cS + q) * cD + d] = cred[sub][t] + cred[sub][t + 128];
  } else {
    int fblk = blk - 256;
    int ns = fblk & 15, tg = fblk >> 4;
    constexpr int P = 130;
    __shared__ __align__(16) float finv[32 * P];
    __shared__ __align__(16) float fb[32 * P];
    __shared__ __align__(16) float xl[32 * 128];
    int t = threadIdx.x;
#pragma unroll
    for (int i = 0; i < 8; ++i) {
      int idx = t + i * 512;
      int rl = idx >> 7, d = idx & 127;
      int g = (ns * 32 + rl) * cD + d;
      finv[rl * P + d] = INV2PI_F / (1.f + fabsf(Wf[g]));
      fb[rl * P + d]   = Bf[g] * INV2PI_F;
      xl[idx] = x[(tg * 32 + rl) * cD + d];
    }
    __syncthreads();
    int nl = t & 31, tli = t >> 5;
#pragma unroll
    for (int p = 0; p < 2; ++p) {
      int tl = p * 16 + tli;
      int T = tg * 32 + tl;
      float srev = (float)(T & 255) * INV2PI_F;
      float uc = 0.f, us = 0.f;
      const float* fi  = finv + nl * P;
      const float* fbp = fb + nl * P;
      const float* xr  = xl + tl * 128;
#pragma unroll 4
      for (int d = 0; d < cD; d += 2) {
        float2 fiv = *(const float2*)(fi + d);
        float2 fbv = *(const float2*)(fbp + d);
        float2 xv  = *(const float2*)(xr + d);
        float f0 = fract1(fmaf(xv.x, fiv.x, fbv.x) + srev);
        float f1 = fract1(fmaf(xv.y, fiv.y, fbv.y) + srev);
        uc += cos_rev(f0);
        us += sin_rev(f0);
        uc += cos_rev(f1);
        us += sin_rev(f1);
      }
      U[T * cN + ns * 32 + nl]  = uc;
      Vv[T * cN + ns * 32 + nl] = us;
    }
  }
}

// ---------------- res projection + attn-out + combine (per layer) ------------
// grid 128 (4 tokens/block) x 512 thr; thread: d4=t&31, tok=(t>>5)&3, nh=t>>7 (4 n-chunks)
__global__ __launch_bounds__(512) void k_res(const float* __restrict__ U, const float* __restrict__ Vv,
                                             const float* __restrict__ pTR, const float* __restrict__ pTI,
                                             const float* __restrict__ ctx, const float* __restrict__ x,
                                             const float* __restrict__ w_out, const float* __restrict__ b_out,
                                             const float* __restrict__ out_scale,
                                             const float* __restrict__ attn_scale, const float* __restrict__ res_scale,
                                             int l, float* __restrict__ xout, unsigned short* __restrict__ xbf) {
  int blk = blockIdx.x;
  int t = threadIdx.x;
  __shared__ __align__(16) float uvU[4][512], uvV[4][512];  // 16KB
  __shared__ __align__(16) float4 part[3][4][32];           // 6KB
#pragma unroll
  for (int i = 0; i < 4; ++i) {
    int idx = t + i * 512;                          // 2048 = 4 tok * 512 n
    int tok = idx >> 9, n = idx & 511;
    uvU[tok][n] = U[(blk * 4 + tok) * cN + n];
    uvV[tok][n] = Vv[(blk * 4 + tok) * cN + n];
  }
  __syncthreads();
  int d4 = t & 31, tok = (t >> 5) & 3, nh = t >> 7;
  int T = blk * 4 + tok, s = T & 255;
  float a0 = 0.f, a1 = 0.f, a2 = 0.f, a3 = 0.f;
  const float* prB = pTR + (size_t)(l * cN) * cD + d4 * 4;
  const float* piB = pTI + (size_t)(l * cN) * cD + d4 * 4;
  int n0 = nh * 128;
#pragma unroll 4
  for (int n = n0; n < n0 + 128; ++n) {
    float4 pr = *(const float4*)(prB + n * cD);
    float4 pi = *(const float4*)(piB + n * cD);
    float wr = uvU[tok][n], wi = uvV[tok][n];
    a0 = fmaf(wr, pr.x, fmaf(wi, pi.x, a0));
    a1 = fmaf(wr, pr.y, fmaf(wi, pi.y, a1));
    a2 = fmaf(wr, pr.z, fmaf(wi, pi.z, a2));
    a3 = fmaf(wr, pr.w, fmaf(wi, pi.w, a3));
  }
  if (nh > 0) part[nh - 1][tok][d4] = make_float4(a0, a1, a2, a3);
  __syncthreads();
  if (nh == 0) {
    float rr[4] = { a0, a1, a2, a3 };
#pragma unroll
    for (int j = 0; j < 3; ++j) {
      float4 p = part[j][tok][d4];
      rr[0] += p.x; rr[1] += p.y; rr[2] += p.z; rr[3] += p.w;
    }
    int di = d4 * 4;
    float4 cx  = *(const float4*)(ctx + T * cD + di);
    float4 wo  = *(const float4*)(w_out + l * cD + di);
    float4 bo  = *(const float4*)(b_out + l * cD + di);
    float4 osc = *(const float4*)(out_scale + l * cD + di);
    float4 xv  = *(const float4*)(x + T * cD + di);
    float as = attn_scale[l], rs = res_scale[l];
    float sphi = (float)s * PHI_F;
    float cxa[4] = { cx.x, cx.y, cx.z, cx.w };
    float woa[4] = { wo.x, wo.y, wo.z, wo.w };
    float boa[4] = { bo.x, bo.y, bo.z, bo.w };
    float osa[4] = { osc.x, osc.y, osc.z, osc.w };
    float xva[4] = { xv.x, xv.y, xv.z, xv.w };
    float oa[4];
#pragma unroll
    for (int c = 0; c < 4; ++c) {
      float th = fmaf(cxa[c], 1.f / (1.f + fabsf(woa[c])), boa[c]) + sphi;
      float f = fract1(th * INV2PI_F);
      float ao = osa[c] * (cos_rev(f) + sin_rev(f));
      float r = rr[c];
      float sil = r / (1.f + __expf(-r));
      oa[c] = fmaf(as, ao, fmaf(rs, sil, xva[c]));
    }
    *(float4*)(xout + T * cD + di) = make_float4(oa[0], oa[1], oa[2], oa[3]);
    if (xbf) {
      ushort4 b4 = { f2bf(oa[0]), f2bf(oa[1]), f2bf(oa[2]), f2bf(oa[3]) };
      *(ushort4*)(xbf + T * cD + di) = b4;
    }
  }
}

// ---------------- final logits GEMM: page-friendly + clean-line writes -------
// grid 792 = 8 m-chunks (outer) x 99 v-chunks of 512 cols (inner). 256 thr = 4 waves.
// Block = 64 m x 512 v; wave = 64 m x 128 v (fm=4, fv=8; acc 128 VGPR).
// Epilogue: per-wave LDS transpose -> full-wave float4 stores (2 rows x 512B per
// instruction); each out row gets a contiguous 2KB burst per block.
__global__ __launch_bounds__(256) void k_gemm(const unsigned short* __restrict__ Xbf,
                                              const unsigned short* __restrict__ Wbf,
                                              float* __restrict__ out) {
  __shared__ __align__(16) float Cst[4][16 * 132];  // 33.8KB: per-wave transpose staging
  int t = threadIdx.x;
  int mchunk = blockIdx.x / 99, vchunk = blockIdx.x % 99;
  int m0 = mchunk * 64;
  int v0 = vchunk * 512;
  int wid = t >> 6, lane = t & 63, lr = lane & 15, lk = lane >> 4;
  int wv = wid * 128;
  const bf16x8* Xp = (const bf16x8*)Xbf;            // row-major: row*16 + ks*4 + lk
  const bf16x8* Wp = (const bf16x8*)Wbf;
  f32x4 acc[4][8];
#pragma unroll
  for (int fm = 0; fm < 4; ++fm)
#pragma unroll
    for (int fv = 0; fv < 8; ++fv) acc[fm][fv] = (f32x4){0.f, 0.f, 0.f, 0.f};
#pragma unroll
  for (int ks = 0; ks < 4; ++ks) {
    bf16x8 a[4];
#pragma unroll
    for (int fm = 0; fm < 4; ++fm)
      a[fm] = Xp[(m0 + fm * 16 + lr) * 16 + ks * 4 + lk];
#pragma unroll
    for (int fv = 0; fv < 8; ++fv) {
      bf16x8 b = Wp[(size_t)(v0 + wv + fv * 16 + lr) * 16 + ks * 4 + lk];
#pragma unroll
      for (int fm = 0; fm < 4; ++fm)
        acc[fm][fv] = __builtin_amdgcn_mfma_f32_16x16x32_bf16(a[fm], b, acc[fm][fv], 0, 0, 0);
    }
  }
  // epilogue: for each fm, transpose 16x128 in LDS then stream float4 stores
  float* Cp = &Cst[wid][0];
  int row2b = lane >> 5;                            // 0/1: row within pair
  int colg  = (lane & 31) * 4;                      // 32 lanes x float4 = 512B
#pragma unroll
  for (int fm = 0; fm < 4; ++fm) {
#pragma unroll
    for (int fv = 0; fv < 8; ++fv)
#pragma unroll
      for (int r = 0; r < 4; ++r)
        Cp[(lk * 4 + r) * 132 + fv * 16 + lr] = acc[fm][fv][r];
#pragma unroll
    for (int step = 0; step < 8; ++step) {
      int rowl = step * 2 + row2b;
      float4 cv = *(const float4*)&Cp[rowl * 132 + colg];
      size_t rb = (size_t)(m0 + fm * 16 + rowl) * cV;
      int cb = v0 + wv + colg;
      if (cb + 3 < cV) {
        *(float4*)(out + rb + cb) = cv;
      } else {
        float ca[4] = { cv.x, cv.y, cv.z, cv.w };
#pragma unroll
        for (int j = 0; j < 4; ++j)
          if (cb + j < cV) out[rb + cb + j] = ca[j];
      }
    }
  }
}

extern "C" void kernel_launch(void* const* d_in, const int* in_sizes, int n_in,
                              void* d_out, int out_size, void* d_ws, size_t ws_size,
                              hipStream_t stream) {
  const int*   tokens    = (const int*)d_in[0];
  const float* emb       = (const float*)d_in[1];
  const float* wq        = (const float*)d_in[2];
  const float* bq        = (const float*)d_in[3];
  const float* wk        = (const float*)d_in[4];
  const float* bk        = (const float*)d_in[5];
  const float* w_out     = (const float*)d_in[6];
  const float* b_out     = (const float*)d_in[7];
  const float* out_scale = (const float*)d_in[8];
  const float* Wf        = (const float*)d_in[9];
  const float* Bf        = (const float*)d_in[10];
  const float* pr        = (const float*)d_in[11];
  const float* pi        = (const float*)d_in[12];
  const float* attn_s    = (const float*)d_in[13];
  const float* res_s     = (const float*)d_in[14];
  const float* out_proj  = (const float*)d_in[15];
  float* out = (float*)d_out;
  float* ws  = (float*)d_ws;

  float*  states = ws;                     // 65536
  float*  x1     = ws + 65536;             // 65536
  float*  x2     = ws + 131072;            // 65536
  float*  ctx    = ws + 196608;            // 65536
  float2* mc     = (float2*)(ws + 262144); // 131072 floats
  float*  U      = ws + 393216;            // 262144
  float*  Vv     = ws + 655360;            // 262144
  float*  pTR    = ws + 917504;            // 131072
  float*  pTI    = ws + 1048576;           // 131072
  unsigned short* X2bf = (unsigned short*)(ws + 1179648); // 65536 ushorts
  unsigned short* Wbf  = (unsigned short*)(ws + 1212416); // 50688*128 ushorts (13.0MB)

  k_setup<<<768 + (cVp * 16) / 256, 256, 0, stream>>>(tokens, emb, mc, pr, pi, pTR, pTI,
                                                      out_proj, Wbf);
  k_scan<<<1, 256, 0, stream>>>(mc, states);

  const float* xin = states;
  float* xouts[2] = { x1, x2 };
  for (int l = 0; l < 2; ++l) {
    k_layer<<<512, 512, 0, stream>>>(xin, states, wq + l * 128, bq + l * 128,
                                     wk + l * 128, bk + l * 128,
                                     Wf + l * 65536, Bf + l * 65536, ctx, U, Vv);
    k_res<<<128, 512, 0, stream>>>(U, Vv, pTR, pTI, ctx, xin, w_out, b_out, out_scale,
                                   attn_s, res_s, l, xouts[l],
                                   (l == 1) ? X2bf : (unsigned short*)nullptr);
    xin = xouts[l];
  }
  k_gemm<<<8 * 99, 256, 0, stream>>>(X2bf, Wbf, out);
}